// Round 3
// baseline (1167.424 us; speedup 1.0000x reference)
//
#include <hip/hip_runtime.h>

typedef unsigned int u32;
typedef unsigned long long u64;
typedef unsigned short u16;

#define NTOT   67108864u    // 8192*8192 = 2^26
#define T0P    7399424u     // candidate threshold (PBASE<<9); true cutoff ~7.5497M
#define PBASE  14452u       // T0P >> 9
#define NSUP   1932u        // supers of 512 fine bins each, covering [T0P, 2^23)
#define NWSEG  8192u        // per-wave segments (2048 blocks x 4 waves)
#define WCAP   1216u        // per-wave cap: mean 869.6, sigma 27.9 -> +12.4 sigma
#define RCAP   4352u        // per-super cap: mean 3686, sigma 60.5 -> +11 sigma
#define KSPLIT 8

struct Scalars {
  double sumW;
  double sumW2;
  u64 npruned;
  u64 nflip;
  float stdf;
  float pad;
};

// ---- ws layout (bytes) ----
#define OFF_COLSUM 0ull           // 2048 u32
#define OFF_ALLOC  8192ull        // 2048 u32
#define OFF_SBASE  16384ull       // 2048 u32
#define OFF_SC     24576ull       // 128 B
#define OFF_SEGCNT 24704ull       // 8192 u32 = 32768
#define OFF_BHIST  57472ull       // 256*2048*4 = 2,097,152
#define OFF_BDEST  2154624ull     // 2,097,152
#define OFF_XBF    4251776ull     // 256*8192*2 = 4,194,304
#define OFF_SEGS   8446080ull     // 8192*1216*4 = 39,845,888
#define OFF_ROUTED 48291968ull    // 8M u32 = 33,554,432
#define OFF_WBF    81846400ull    // optional bf16 W copy: 128 MB
#define WS_NEED_WBF 216064128ull  // OFF_WBF + 134217728
#define ROUTED_CAP 8388608u
// gemm partials REUSE segs+routed region (dead after k_rank):
// OFF_OUTP..OFF_OUTP+KSPLIT*8MB = 8446080 + 67108864 = 75,554,944 < OFF_WBF ok
#define OFF_OUTP   OFF_SEGS

// JAX Threefry-2x32, 20 rounds — verified vs known-answer vector
__host__ __device__ inline void tf2x32(u32 k0, u32 k1, u32 x0, u32 x1, u32& y0, u32& y1) {
  u32 ks2 = k0 ^ k1 ^ 0x1BD11BDAu;
  x0 += k0; x1 += k1;
#define TFR(r) { x0 += x1; x1 = (x1 << (r)) | (x1 >> (32 - (r))); x1 ^= x0; }
  TFR(13) TFR(15) TFR(26) TFR(6)  x0 += k1;  x1 += ks2 + 1u;
  TFR(17) TFR(29) TFR(16) TFR(24) x0 += ks2; x1 += k0 + 2u;
  TFR(13) TFR(15) TFR(26) TFR(6)  x0 += k0;  x1 += k1 + 3u;
  TFR(17) TFR(29) TFR(16) TFR(24) x0 += k1;  x1 += ks2 + 4u;
  TFR(13) TFR(15) TFR(26) TFR(6)  x0 += ks2; x1 += k0 + 5u;
#undef TFR
  y0 = x0; y1 = x1;
}

// Partitionable-mode bits for element i: counter (0, i), bits = y0 ^ y1
__device__ inline u32 jax_bits32(u32 k0, u32 k1, u32 i) {
  u32 y0, y1; tf2x32(k0, k1, 0u, i, y0, y1);
  return y0 ^ y1;
}

__device__ inline u16 f2bf(float f) {
  union { float f; u32 u; } c; c.f = f;
  u32 r = ((c.u >> 16) & 1u) + 0x7FFFu;   // RNE
  return (u16)((c.u + r) >> 16);
}

__device__ inline u32 mbcnt64(u64 m) {
  return __builtin_amdgcn_mbcnt_hi((u32)(m >> 32),
         __builtin_amdgcn_mbcnt_lo((u32)m, 0u));
}

// XLA ErfInv (f32, Giles)
__device__ inline float erfinv32(float x) {
  float w = -log1pf(-x * x);
  float p;
  if (w < 5.0f) {
    w -= 2.5f;
    p = 2.81022636e-08f;
    p = fmaf(p, w, 3.43273939e-07f);
    p = fmaf(p, w, -3.5233877e-06f);
    p = fmaf(p, w, -4.39150654e-06f);
    p = fmaf(p, w, 0.00021858087f);
    p = fmaf(p, w, -0.00125372503f);
    p = fmaf(p, w, -0.00417768164f);
    p = fmaf(p, w, 0.246640727f);
    p = fmaf(p, w, 1.50140941f);
  } else {
    w = sqrtf(w) - 3.0f;
    p = -0.000200214257f;
    p = fmaf(p, w, 0.000100950558f);
    p = fmaf(p, w, 0.00134934322f);
    p = fmaf(p, w, -0.00367342844f);
    p = fmaf(p, w, 0.00573950773f);
    p = fmaf(p, w, -0.0076224613f);
    p = fmaf(p, w, 0.00943887047f);
    p = fmaf(p, w, 1.00167406f);
    p = fmaf(p, w, 2.83297682f);
  }
  return p * x;
}

// Pass 1: stream W (2x float4 = 8 elem/iter); f64 sums; 8 independent threefry
// chains (ILP); candidate append via ballot+mbcnt. NO stores except candidates
// (the round-1 wbf store in this loop cost ~110us of vmcnt serialization).
__global__ __launch_bounds__(256) void k_pass1(const float* __restrict__ W,
                                               Scalars* sc, u32* segcnt, u32* segs,
                                               u32 uk0, u32 uk1) {
  u32 t = threadIdx.x;
  u32 gid = blockIdx.x * 256 + t;
  u32 lane = t & 63;
  u32 wid = gid >> 6;
  u32* wseg = segs + (u64)wid * WCAP;
  u32 wbase = 0;                     // wave-uniform cursor (SGPR)
  double s = 0.0, s2 = 0.0; u32 cnt = 0;
  const u32 stride8 = 2048u * 256u * 8u;
  for (u32 b8 = gid * 8; b8 < NTOT; b8 += stride8) {
    float4 wa = *(const float4*)(W + b8);
    float4 wb = *(const float4*)(W + b8 + 4);
    u32 sb[8];
#pragma unroll
    for (int e = 0; e < 8; e++) sb[e] = jax_bits32(uk0, uk1, b8 + (u32)e) >> 9;
    float we[8] = {wa.x, wa.y, wa.z, wa.w, wb.x, wb.y, wb.z, wb.w};
#pragma unroll
    for (int e = 0; e < 8; e++) {
      float w = we[e];
      s  += (double)w;
      s2 += (double)w * (double)w;
      bool pr = (w == 0.0f);
      cnt += pr ? 1u : 0u;
      bool c = pr && (sb[e] >= T0P);
      u64 m = __ballot(c ? 1 : 0);
      if (c) {
        u32 pos = wbase + mbcnt64(m);      // exclusive prefix among set lanes
        if (pos < WCAP) wseg[pos] = b8 + (u32)e;
      }
      wbase += (u32)__popcll(m);
    }
  }
  for (int o = 32; o > 0; o >>= 1) {
    s += __shfl_down(s, o); s2 += __shfl_down(s2, o); cnt += __shfl_down(cnt, o);
  }
  if (lane == 0) {
    atomicAdd(&sc->sumW, s);
    atomicAdd(&sc->sumW2, s2);
    atomicAdd(&sc->npruned, (u64)cnt);
    segcnt[wid] = (wbase > WCAP) ? WCAP : wbase;
  }
}

// Dedicated streaming W f32 -> bf16 convert (runs BEFORE rank; rank scatters
// flips into wbf afterwards, W itself is never modified in the wbf path).
__global__ __launch_bounds__(256) void k_wconv(const float* __restrict__ W,
                                               u16* __restrict__ wbf) {
  u32 i = blockIdx.x * 256 + threadIdx.x;
  const u32 stride = 4096u * 256u;
  for (u32 g = i; g < NTOT / 8; g += stride) {
    const float4* p = (const float4*)(W + (u64)g * 8);
    float4 a = p[0], b = p[1];
    uint4 o;
    o.x = (u32)f2bf(a.x) | ((u32)f2bf(a.y) << 16);
    o.y = (u32)f2bf(a.z) | ((u32)f2bf(a.w) << 16);
    o.z = (u32)f2bf(b.x) | ((u32)f2bf(b.y) << 16);
    o.w = (u32)f2bf(b.z) | ((u32)f2bf(b.w) << 16);
    *(uint4*)(wbf + (u64)g * 8) = o;
  }
}

// Route A: per-block super-histogram (LDS only) -> bhist[block][2048] row.
__global__ __launch_bounds__(256) void k_route_a(const u32* __restrict__ segs,
                                                 const u32* __restrict__ segcnt,
                                                 u32* bhist, u32 uk0, u32 uk1) {
  __shared__ u32 lhist[2048];
  u32 t = threadIdx.x;
  for (u32 j = t; j < 2048; j += 256) lhist[j] = 0;
  __syncthreads();
#pragma unroll 1
  for (int sg = 0; sg < 32; sg++) {
    u32 wid = blockIdx.x * 32 + sg;
    u32 n = segcnt[wid]; if (n > WCAP) n = WCAP;
    const u32* sp = segs + (u64)wid * WCAP;
    for (u32 i = t; i < n; i += 256) {
      u32 sup = (jax_bits32(uk0, uk1, sp[i]) >> 18) - PBASE;
      atomicAdd(&lhist[sup], 1u);
    }
  }
  __syncthreads();
  for (u32 j = t; j < 2048; j += 256) bhist[blockIdx.x * 2048 + j] = lhist[j];
}

// Column scan: per super s, exclusive prefix of bhist[b][s] over blocks b + totals.
__global__ __launch_bounds__(256) void k_colscan(const u32* __restrict__ bhist,
                                                 u32* bdest, u32* colsum) {
  __shared__ u32 wtmp[4];
  u32 s = blockIdx.x, t = threadIdx.x, lane = t & 63, wv = t >> 6;
  u32 v = bhist[t * 2048 + s];
  u32 inc = v;
#pragma unroll
  for (int o = 1; o < 64; o <<= 1) { u32 x = (u32)__shfl_up((int)inc, o); if (lane >= (u32)o) inc += x; }
  if (lane == 63) wtmp[wv] = inc;
  __syncthreads();
  u32 woff = 0;
  for (u32 w = 0; w < wv; w++) woff += wtmp[w];
  bdest[t * 2048 + s] = woff + inc - v;
  if (t == 255) colsum[s] = woff + inc;
}

// Scalars + 2048-wide prefix (alloc = routed layout) & suffix (sbase = rank base).
__global__ __launch_bounds__(256) void k_scan(const u32* __restrict__ colsum, Scalars* sc,
                                              u32* alloc, u32* sbase) {
  __shared__ u32 h[2048];
  __shared__ u32 wtmp[4];
  u32 t = threadIdx.x, lane = t & 63, wv = t >> 6;
  for (u32 j = t; j < 2048; j += 256) h[j] = colsum[j];
  __syncthreads();
  {
    u32 a[8]; u32 s8 = 0;
#pragma unroll
    for (int k = 0; k < 8; k++) { a[k] = h[t * 8 + k]; s8 += a[k]; }
    u32 inc = s8;
#pragma unroll
    for (int o = 1; o < 64; o <<= 1) { u32 v = (u32)__shfl_up((int)inc, o); if (lane >= (u32)o) inc += v; }
    if (lane == 63) wtmp[wv] = inc;
    __syncthreads();
    u32 woff = 0; for (u32 w = 0; w < wv; w++) woff += wtmp[w];
    u32 base = woff + inc - s8;
#pragma unroll
    for (int k = 0; k < 8; k++) { alloc[t * 8 + k] = base; base += a[k]; }
    __syncthreads();
  }
  {
    u32 a[8]; u32 s8 = 0;
#pragma unroll
    for (int k = 0; k < 8; k++) { a[k] = h[2047 - (t * 8 + k)]; s8 += a[k]; }
    u32 inc = s8;
#pragma unroll
    for (int o = 1; o < 64; o <<= 1) { u32 v = (u32)__shfl_up((int)inc, o); if (lane >= (u32)o) inc += v; }
    if (lane == 63) wtmp[wv] = inc;
    __syncthreads();
    u32 woff = 0; for (u32 w = 0; w < wv; w++) woff += wtmp[w];
    u32 base = woff + inc - s8;
#pragma unroll
    for (int k = 0; k < 8; k++) { sbase[2047 - (t * 8 + k)] = base; base += a[k]; }
  }
  if (t == 0) {
    double nk = (double)NTOT - (double)sc->npruned;
    double mean = sc->sumW / nk;
    double var = (sc->sumW2 - 2.0 * mean * sc->sumW + nk * mean * mean) / (nk - 1.0);
    sc->stdf = (float)sqrt(var);
    u64 nfi = (u64)(0.1 * (double)sc->npruned);
    if (nfi < 1) nfi = 1;
    sc->nflip = nfi;
  }
}

// Route B: re-stream segments; LDS cursors pre-seeded from alloc+bdest.
__global__ __launch_bounds__(256) void k_route_b(const u32* __restrict__ segs,
                                                 const u32* __restrict__ segcnt,
                                                 const u32* __restrict__ alloc,
                                                 const u32* __restrict__ bdest,
                                                 u32* routed, u32 uk0, u32 uk1) {
  __shared__ u32 lcur[2048];
  u32 t = threadIdx.x;
  for (u32 j = t; j < 2048; j += 256) lcur[j] = alloc[j] + bdest[blockIdx.x * 2048 + j];
  __syncthreads();
#pragma unroll 1
  for (int sg = 0; sg < 32; sg++) {
    u32 wid = blockIdx.x * 32 + sg;
    u32 n = segcnt[wid]; if (n > WCAP) n = WCAP;
    const u32* sp = segs + (u64)wid * WCAP;
    for (u32 i = t; i < n; i += 256) {
      u32 idx = sp[i];
      u32 sup = (jax_bits32(uk0, uk1, idx) >> 18) - PBASE;
      u32 pos = atomicAdd(&lcur[sup], 1u);
      if (pos < ROUTED_CAP) routed[pos] = idx;
    }
  }
}

// 512-bin suffix-exclusive scan (256 threads, 2 bins each)
__device__ inline void suf512(const u32* cnt, u32* suf, u32* wtmp) {
  u32 t = threadIdx.x, lane = t & 63, wv = t >> 6;
  u32 a0 = cnt[511 - t * 2], a1 = cnt[510 - t * 2];
  u32 s = a0 + a1;
  u32 inc = s;
#pragma unroll
  for (int o = 1; o < 64; o <<= 1) { u32 v = (u32)__shfl_up((int)inc, o); if (lane >= (u32)o) inc += v; }
  if (lane == 63) wtmp[wv] = inc;
  __syncthreads();
  u32 woff = 0;
  for (u32 w = 0; w < wv; w++) woff += wtmp[w];
  u32 base = woff + inc - s;
  suf[511 - t * 2] = base;
  suf[510 - t * 2] = base + a0;
  __syncthreads();
}

// Rank: one block per 512-bin super. Winners write flip value: bf16 into wbf
// (WBF path: half the scatter RMW traffic, W untouched) or fp32 into W.
template<int WBF>
__global__ __launch_bounds__(256) void k_rank(float* __restrict__ W,
                                              u16* __restrict__ wbf,
                                              const u32* __restrict__ colsum,
                                              const u32* __restrict__ alloc,
                                              const u32* __restrict__ sbase,
                                              const u32* __restrict__ routed,
                                              const Scalars* __restrict__ sc,
                                              u32 uk0, u32 uk1, u32 vk0, u32 vk1) {
  u32 p = blockIdx.x;
  u32 n = colsum[p]; if (n == 0) return;
  if (n > RCAP) n = RCAP;
  u64 nflip = sc->nflip;
  u32 rbase = sbase[p];
  if ((u64)rbase >= nflip) return;
  __shared__ u32 sIdx[RCAP];
  __shared__ u16 sFine[RCAP];
  __shared__ u32 pIdx[RCAP];
  __shared__ u32 hist[512], gbase[512], cur[512], wtmp[4];
  u32 t = threadIdx.x;
  for (u32 j = t; j < 512; j += 256) hist[j] = 0;
  __syncthreads();
  const u32* src = routed + alloc[p];
  for (u32 i = t; i < n; i += 256) {
    u32 idx = src[i];
    u32 f = (jax_bits32(uk0, uk1, idx) >> 9) & 511u;
    sIdx[i] = idx;
    sFine[i] = (u16)f;
    atomicAdd(&hist[f], 1u);
  }
  __syncthreads();
  suf512(hist, gbase, wtmp);         // gbase[f] = # members with fine > f
  for (u32 j = t; j < 512; j += 256) cur[j] = gbase[j];
  __syncthreads();
  for (u32 i = t; i < n; i += 256) {
    u32 pos = atomicAdd(&cur[sFine[i]], 1u);
    pIdx[pos] = sIdx[i];
  }
  __syncthreads();
  float stdf = sc->stdf;
  for (u32 i = t; i < n; i += 256) {
    u32 f = sFine[i];
    u32 g0 = gbase[f], g1 = g0 + hist[f];
    u32 v = sIdx[i];
    u32 ord = 0;
    for (u32 q = g0; q < g1; q++) ord += (pIdx[q] < v) ? 1u : 0u;
    u64 rank = (u64)rbase + g0 + ord;
    if (rank >= nflip) continue;
    u32 bits = jax_bits32(vk0, vk1, (u32)rank);
    union { u32 u; float fl; } cv; cv.u = 0x3F800000u | (bits >> 9);
    float fu = cv.fl - 1.0f;               // uniform [0,1)
    const float lo = -0.99999994f;         // nextafter(-1,0); (1-lo) rounds to 2.0f
    float u2 = fmaxf(lo, fu * 2.0f + lo);  // uniform [lo, 1)
    float nrm = 1.41421354f * erfinv32(u2);
    float val = (nrm * stdf) * 0.1f;
    if (WBF) wbf[v] = f2bf(val);
    else     W[v] = val;
  }
}

// x fp32 -> bf16 once
__global__ __launch_bounds__(256) void k_xconv(const float* __restrict__ x, u16* __restrict__ xbf) {
  u32 i = blockIdx.x * blockDim.x + threadIdx.x;
  float4 v = ((const float4*)x)[i];
  ushort4 o; o.x = f2bf(v.x); o.y = f2bf(v.y); o.z = f2bf(v.z); o.w = f2bf(v.w);
  ((ushort4*)xbf)[i] = o;
}

// GEMM: out[m][n] = sum_k x[m][k] * W[n][k]. M=256 full per block, N tile 64,
// split-K=8, partial outputs to ws (no global atomics), reduced by k_redout.
typedef __bf16 bf16x8 __attribute__((ext_vector_type(8)));
typedef float f32x4 __attribute__((ext_vector_type(4)));

template<int WBF>
__global__ __launch_bounds__(256, 2) void k_gemm(const u16* __restrict__ xbf,
                                                 const float* __restrict__ W,
                                                 const u16* __restrict__ wbf,
                                                 float* __restrict__ outp) {
  __shared__ u16 xs[256 * 72];
  __shared__ u16 wsm[64 * 72];
  u32 tid = threadIdx.x;
  u32 lane = tid & 63, wv = tid >> 6;
  u32 nt0 = blockIdx.x * 64;
  u32 kbase = blockIdx.y * (8192 / KSPLIT);
  f32x4 acc[4][4];
#pragma unroll
  for (int i = 0; i < 4; i++)
#pragma unroll
    for (int j = 0; j < 4; j++) acc[i][j] = (f32x4){0.f, 0.f, 0.f, 0.f};

  for (u32 kb = kbase; kb < kbase + (8192u / KSPLIT); kb += 64u) {
#pragma unroll
    for (int r8 = 0; r8 < 8; r8++) {
      u32 row = r8 * 32 + (tid >> 3);
      u32 kseg = (tid & 7) * 8;
      uint4 v = *(const uint4*)(xbf + (u64)row * 8192 + kb + kseg);
      *(uint4*)&xs[row * 72 + kseg] = v;
    }
    if (WBF) {
#pragma unroll
      for (int r = 0; r < 2; r++) {
        u32 f = r * 256 + tid;
        u32 row = f >> 3;
        u32 kc = (f & 7) * 8;
        uint4 v = *(const uint4*)(wbf + (u64)(nt0 + row) * 8192 + kb + kc);
        *(uint4*)&wsm[row * 72 + kc] = v;
      }
    } else {
#pragma unroll
      for (int r = 0; r < 4; r++) {
        u32 f4 = r * 256 + tid;
        u32 row = f4 >> 4;
        u32 kc = (f4 & 15) * 4;
        float4 v = *(const float4*)(W + (u64)(nt0 + row) * 8192 + kb + kc);
        ushort4 o; o.x = f2bf(v.x); o.y = f2bf(v.y); o.z = f2bf(v.z); o.w = f2bf(v.w);
        *(ushort4*)&wsm[row * 72 + kc] = o;
      }
    }
    __syncthreads();
#pragma unroll
    for (int ks = 0; ks < 2; ks++) {
      bf16x8 a[4], b[4];
      u32 koff = ks * 32 + (lane >> 4) * 8;
      u32 rsel = lane & 15;
#pragma unroll
      for (int mt = 0; mt < 4; mt++) a[mt] = *(bf16x8*)&xs[(wv * 64 + mt * 16 + rsel) * 72 + koff];
#pragma unroll
      for (int nt = 0; nt < 4; nt++) b[nt] = *(bf16x8*)&wsm[(nt * 16 + rsel) * 72 + koff];
#pragma unroll
      for (int mt = 0; mt < 4; mt++)
#pragma unroll
        for (int nt = 0; nt < 4; nt++)
          acc[mt][nt] = __builtin_amdgcn_mfma_f32_16x16x32_bf16(a[mt], b[nt], acc[mt][nt], 0, 0, 0);
    }
    __syncthreads();
  }
  float* op = outp + (u64)blockIdx.y * 2097152u;
  u32 quad = lane >> 4, col = lane & 15;
#pragma unroll
  for (int mt = 0; mt < 4; mt++)
#pragma unroll
    for (int nt = 0; nt < 4; nt++) {
      u32 n = nt0 + nt * 16 + col;
#pragma unroll
      for (int rg = 0; rg < 4; rg++) {
        u32 m = wv * 64 + mt * 16 + quad * 4 + rg;
        op[(u64)m * 8192 + n] = acc[mt][nt][rg];
      }
    }
}

// Reduce split-K partials -> out. Fully writes out (no memset needed).
__global__ __launch_bounds__(256) void k_redout(const float* __restrict__ part,
                                                float* __restrict__ out) {
  u32 i = blockIdx.x * 256 + threadIdx.x;   // f32x4 group, 2M/4 = 524288 total
  float4 s = ((const float4*)part)[i];
#pragma unroll
  for (int k = 1; k < KSPLIT; k++) {
    float4 v = ((const float4*)(part + (u64)k * 2097152u))[i];
    s.x += v.x; s.y += v.y; s.z += v.z; s.w += v.w;
  }
  ((float4*)out)[i] = s;
}

extern "C" void kernel_launch(void* const* d_in, const int* in_sizes, int n_in,
                              void* d_out, int out_size, void* d_ws, size_t ws_size,
                              hipStream_t stream) {
  const float* x; float* W;
  if (in_sizes[0] == 2097152) { x = (const float*)d_in[0]; W = (float*)d_in[1]; }
  else                        { x = (const float*)d_in[1]; W = (float*)d_in[0]; }
  float* out = (float*)d_out;
  char* ws = (char*)d_ws;

  u32* colsum = (u32*)(ws + OFF_COLSUM);
  u32* alloc  = (u32*)(ws + OFF_ALLOC);
  u32* sbase  = (u32*)(ws + OFF_SBASE);
  Scalars* sc = (Scalars*)(ws + OFF_SC);
  u32* segcnt = (u32*)(ws + OFF_SEGCNT);
  u32* bhist  = (u32*)(ws + OFF_BHIST);
  u32* bdest  = (u32*)(ws + OFF_BDEST);
  u16* xbf    = (u16*)(ws + OFF_XBF);
  u32* segs   = (u32*)(ws + OFF_SEGS);
  u32* routed = (u32*)(ws + OFF_ROUTED);
  u16* wbf    = (u16*)(ws + OFF_WBF);
  float* outp = (float*)(ws + OFF_OUTP);

  bool usewbf = (ws_size >= (size_t)WS_NEED_WBF);

  // PARTITIONABLE split of key(42): key[i] = threefry(k=(0,42), counter=(0,i))
  u32 a0, a1, b0, b1;
  tf2x32(0u, 42u, 0u, 0u, a0, a1);   // ks -> uniform scores
  tf2x32(0u, 42u, 0u, 1u, b0, b1);   // kv -> normal vals

  hipMemsetAsync(sc, 0, sizeof(Scalars), stream);

  k_xconv<<<2048, 256, 0, stream>>>(x, xbf);
  k_pass1<<<2048, 256, 0, stream>>>(W, sc, segcnt, segs, a0, a1);
  if (usewbf) k_wconv<<<4096, 256, 0, stream>>>(W, wbf);
  k_route_a<<<256, 256, 0, stream>>>(segs, segcnt, bhist, a0, a1);
  k_colscan<<<2048, 256, 0, stream>>>(bhist, bdest, colsum);
  k_scan<<<1, 256, 0, stream>>>(colsum, sc, alloc, sbase);
  k_route_b<<<256, 256, 0, stream>>>(segs, segcnt, alloc, bdest, routed, a0, a1);
  if (usewbf) k_rank<1><<<NSUP, 256, 0, stream>>>(W, wbf, colsum, alloc, sbase, routed, sc, a0, a1, b0, b1);
  else        k_rank<0><<<NSUP, 256, 0, stream>>>(W, wbf, colsum, alloc, sbase, routed, sc, a0, a1, b0, b1);
  dim3 g(128, KSPLIT);
  if (usewbf) k_gemm<1><<<g, 256, 0, stream>>>(xbf, W, wbf, outp);
  else        k_gemm<0><<<g, 256, 0, stream>>>(xbf, W, wbf, outp);
  k_redout<<<2048, 256, 0, stream>>>(outp, out);
}

// Round 4
// 1025.404 us; speedup vs baseline: 1.1385x; 1.1385x over previous
//
#include <hip/hip_runtime.h>

typedef unsigned int u32;
typedef unsigned long long u64;
typedef unsigned short u16;

#define NTOT   67108864u    // 8192*8192 = 2^26
#define T0P    7399424u     // candidate threshold (PBASE<<9); true cutoff ~7.5497M
#define PBASE  14452u       // T0P >> 9
#define NSUP   1932u        // supers of 512 fine bins each, covering [T0P, 2^23)
#define NWSEG  4096u        // per-wave segments (1024 blocks x 4 waves)
#define WCAP   2176u        // per-wave cap: mean 1739, sigma 39.4 -> +11.1 sigma
#define RCAP   4352u        // per-super cap: mean 3686, sigma 60.5 -> +11 sigma
#define KSPLIT 8            // gemm2 split-K (1024 blocks)

struct Scalars {
  double sumW;
  double sumW2;
  u64 npruned;
  u64 nflip;
  float stdf;
  float pad;
};

// ---- ws layout (bytes) ---- (round-0 geometry + wbf appendix)
#define OFF_COLSUM 0ull          // 2048 u32
#define OFF_ALLOC  8192ull       // 2048 u32
#define OFF_SBASE  16384ull      // 2048 u32
#define OFF_SC     24576ull      // 128 B
#define OFF_SEGCNT 24704ull      // 4096 u32 -> ends 41088
#define OFF_BHIST  41216ull      // 256*2048*4 = 2,097,152
#define OFF_BDEST  2138368ull    // 2,097,152
#define OFF_XBF    4235520ull    // 256*8192*2 = 4,194,304
#define OFF_SEGS   8429824ull    // 4096*2176*4 = 35,651,584 -> ends 44,081,408
#define OFF_ROUTED 44081408ull   // 35,651,584 -> ends 79,732,992
#define OFF_WBF    81846400ull   // bf16 W copy: 134,217,728 -> ends 216,064,128
#define WS_NEED_WBF 216064128ull
#define ROUTED_CAP 8912896u
// gemm2 partials REUSE segs+routed (dead after k_rank):
// 8,429,824 + 8*8,388,608 = 75,538,688 < OFF_WBF  ok
#define OFF_OUTP   OFF_SEGS

// JAX Threefry-2x32, 20 rounds — verified vs known-answer vector
__host__ __device__ inline void tf2x32(u32 k0, u32 k1, u32 x0, u32 x1, u32& y0, u32& y1) {
  u32 ks2 = k0 ^ k1 ^ 0x1BD11BDAu;
  x0 += k0; x1 += k1;
#define TFR(r) { x0 += x1; x1 = (x1 << (r)) | (x1 >> (32 - (r))); x1 ^= x0; }
  TFR(13) TFR(15) TFR(26) TFR(6)  x0 += k1;  x1 += ks2 + 1u;
  TFR(17) TFR(29) TFR(16) TFR(24) x0 += ks2; x1 += k0 + 2u;
  TFR(13) TFR(15) TFR(26) TFR(6)  x0 += k0;  x1 += k1 + 3u;
  TFR(17) TFR(29) TFR(16) TFR(24) x0 += k1;  x1 += ks2 + 4u;
  TFR(13) TFR(15) TFR(26) TFR(6)  x0 += ks2; x1 += k0 + 5u;
#undef TFR
  y0 = x0; y1 = x1;
}

// Partitionable-mode bits for element i: counter (0, i), bits = y0 ^ y1
__device__ inline u32 jax_bits32(u32 k0, u32 k1, u32 i) {
  u32 y0, y1; tf2x32(k0, k1, 0u, i, y0, y1);
  return y0 ^ y1;
}

__device__ inline u16 f2bf(float f) {
  union { float f; u32 u; } c; c.f = f;
  u32 r = ((c.u >> 16) & 1u) + 0x7FFFu;   // RNE
  return (u16)((c.u + r) >> 16);
}

// XLA ErfInv (f32, Giles)
__device__ inline float erfinv32(float x) {
  float w = -log1pf(-x * x);
  float p;
  if (w < 5.0f) {
    w -= 2.5f;
    p = 2.81022636e-08f;
    p = fmaf(p, w, 3.43273939e-07f);
    p = fmaf(p, w, -3.5233877e-06f);
    p = fmaf(p, w, -4.39150654e-06f);
    p = fmaf(p, w, 0.00021858087f);
    p = fmaf(p, w, -0.00125372503f);
    p = fmaf(p, w, -0.00417768164f);
    p = fmaf(p, w, 0.246640727f);
    p = fmaf(p, w, 1.50140941f);
  } else {
    w = sqrtf(w) - 3.0f;
    p = -0.000200214257f;
    p = fmaf(p, w, 0.000100950558f);
    p = fmaf(p, w, 0.00134934322f);
    p = fmaf(p, w, -0.00367342844f);
    p = fmaf(p, w, 0.00573950773f);
    p = fmaf(p, w, -0.0076224613f);
    p = fmaf(p, w, 0.00943887047f);
    p = fmaf(p, w, 1.00167406f);
    p = fmaf(p, w, 2.83297682f);
  }
  return p * x;
}

// Pass 1 (round-0 verbatim — best measured: 270us): stream W (float4); f64 sums;
// 4 independent threefry chains; candidate append to per-wave segment with
// register cursor via shfl-scan. Ballot+mbcnt variant measured WORSE (355us).
__global__ __launch_bounds__(256) void k_pass1(const float* __restrict__ W, Scalars* sc,
                                               u32* segcnt, u32* segs, u32 uk0, u32 uk1) {
  u32 t = threadIdx.x;
  u32 gid = blockIdx.x * 256 + t;
  u32 lane = t & 63;
  u32 wid = gid >> 6;
  u32* wseg = segs + (u64)wid * WCAP;
  u32 wbase = 0;                     // wave-uniform cursor, kept in registers
  double s = 0.0, s2 = 0.0; u32 cnt = 0;
  const u32 stride4 = 1024u * 256u * 4u;
  for (u32 b4 = gid * 4; b4 < NTOT; b4 += stride4) {
    float4 w4 = *(const float4*)(W + b4);
    u32 sb0 = jax_bits32(uk0, uk1, b4 + 0) >> 9;   // 4 independent chains
    u32 sb1 = jax_bits32(uk0, uk1, b4 + 1) >> 9;
    u32 sb2 = jax_bits32(uk0, uk1, b4 + 2) >> 9;
    u32 sb3 = jax_bits32(uk0, uk1, b4 + 3) >> 9;
    float we[4] = {w4.x, w4.y, w4.z, w4.w};
    u32 sbv[4] = {sb0, sb1, sb2, sb3};
    u32 cand[4]; u32 nc = 0;
#pragma unroll
    for (int e = 0; e < 4; e++) {
      float w = we[e];
      s  += (double)w;
      s2 += (double)w * (double)w;
      bool pr = (w == 0.0f);
      cnt += pr ? 1u : 0u;
      if (pr && sbv[e] >= T0P) { cand[nc] = b4 + e; nc++; }
    }
    u32 inc = nc;                    // wave inclusive scan of per-lane counts
#pragma unroll
    for (int o = 1; o < 64; o <<= 1) { u32 v = (u32)__shfl_up((int)inc, o); if (lane >= (u32)o) inc += v; }
    u32 tot = (u32)__shfl((int)inc, 63);
    u32 pos = wbase + inc - nc;
    for (u32 k2 = 0; k2 < nc; k2++)
      if (pos + k2 < WCAP) wseg[pos + k2] = cand[k2];
    wbase += tot;
  }
  for (int o = 32; o > 0; o >>= 1) {
    s += __shfl_down(s, o); s2 += __shfl_down(s2, o); cnt += __shfl_down(cnt, o);
  }
  if (lane == 0) {
    atomicAdd(&sc->sumW, s);
    atomicAdd(&sc->sumW2, s2);
    atomicAdd(&sc->npruned, (u64)cnt);
    segcnt[wid] = (wbase > WCAP) ? WCAP : wbase;
  }
}

// Dedicated streaming W f32 -> bf16 convert. Runs before rank (rank scatters
// flips into wbf; W itself is never modified in the wbf path). Earns its
// ~75us by unlocking global_load_lds bf16 staging in k_gemm2.
__global__ __launch_bounds__(256) void k_wconv(const float* __restrict__ W,
                                               u16* __restrict__ wbf) {
  u32 i = blockIdx.x * 256 + threadIdx.x;
  const u32 stride = 4096u * 256u;
  for (u32 g = i; g < NTOT / 8; g += stride) {
    const float4* p = (const float4*)(W + (u64)g * 8);
    float4 a = p[0], b = p[1];
    uint4 o;
    o.x = (u32)f2bf(a.x) | ((u32)f2bf(a.y) << 16);
    o.y = (u32)f2bf(a.z) | ((u32)f2bf(a.w) << 16);
    o.z = (u32)f2bf(b.x) | ((u32)f2bf(b.y) << 16);
    o.w = (u32)f2bf(b.z) | ((u32)f2bf(b.w) << 16);
    *(uint4*)(wbf + (u64)g * 8) = o;
  }
}

// Route A: per-block super-histogram (LDS only) -> bhist[block][2048] row.
__global__ __launch_bounds__(256) void k_route_a(const u32* __restrict__ segs,
                                                 const u32* __restrict__ segcnt,
                                                 u32* bhist, u32 uk0, u32 uk1) {
  __shared__ u32 lhist[2048];
  u32 t = threadIdx.x;
  for (u32 j = t; j < 2048; j += 256) lhist[j] = 0;
  __syncthreads();
#pragma unroll 1
  for (int sg = 0; sg < 16; sg++) {
    u32 wid = blockIdx.x * 16 + sg;
    u32 n = segcnt[wid]; if (n > WCAP) n = WCAP;
    const u32* sp = segs + (u64)wid * WCAP;
    for (u32 i = t; i < n; i += 256) {
      u32 sup = (jax_bits32(uk0, uk1, sp[i]) >> 18) - PBASE;
      atomicAdd(&lhist[sup], 1u);
    }
  }
  __syncthreads();
  for (u32 j = t; j < 2048; j += 256) bhist[blockIdx.x * 2048 + j] = lhist[j];
}

// Column scan: per super s, exclusive prefix of bhist[b][s] over blocks b + totals.
__global__ __launch_bounds__(256) void k_colscan(const u32* __restrict__ bhist,
                                                 u32* bdest, u32* colsum) {
  __shared__ u32 wtmp[4];
  u32 s = blockIdx.x, t = threadIdx.x, lane = t & 63, wv = t >> 6;
  u32 v = bhist[t * 2048 + s];
  u32 inc = v;
#pragma unroll
  for (int o = 1; o < 64; o <<= 1) { u32 x = (u32)__shfl_up((int)inc, o); if (lane >= (u32)o) inc += x; }
  if (lane == 63) wtmp[wv] = inc;
  __syncthreads();
  u32 woff = 0;
  for (u32 w = 0; w < wv; w++) woff += wtmp[w];
  bdest[t * 2048 + s] = woff + inc - v;
  if (t == 255) colsum[s] = woff + inc;
}

// Scalars + 2048-wide prefix (alloc = routed layout) & suffix (sbase = rank base).
__global__ __launch_bounds__(256) void k_scan(const u32* __restrict__ colsum, Scalars* sc,
                                              u32* alloc, u32* sbase) {
  __shared__ u32 h[2048];
  __shared__ u32 wtmp[4];
  u32 t = threadIdx.x, lane = t & 63, wv = t >> 6;
  for (u32 j = t; j < 2048; j += 256) h[j] = colsum[j];
  __syncthreads();
  {
    u32 a[8]; u32 s8 = 0;
#pragma unroll
    for (int k = 0; k < 8; k++) { a[k] = h[t * 8 + k]; s8 += a[k]; }
    u32 inc = s8;
#pragma unroll
    for (int o = 1; o < 64; o <<= 1) { u32 v = (u32)__shfl_up((int)inc, o); if (lane >= (u32)o) inc += v; }
    if (lane == 63) wtmp[wv] = inc;
    __syncthreads();
    u32 woff = 0; for (u32 w = 0; w < wv; w++) woff += wtmp[w];
    u32 base = woff + inc - s8;
#pragma unroll
    for (int k = 0; k < 8; k++) { alloc[t * 8 + k] = base; base += a[k]; }
    __syncthreads();
  }
  {
    u32 a[8]; u32 s8 = 0;
#pragma unroll
    for (int k = 0; k < 8; k++) { a[k] = h[2047 - (t * 8 + k)]; s8 += a[k]; }
    u32 inc = s8;
#pragma unroll
    for (int o = 1; o < 64; o <<= 1) { u32 v = (u32)__shfl_up((int)inc, o); if (lane >= (u32)o) inc += v; }
    if (lane == 63) wtmp[wv] = inc;
    __syncthreads();
    u32 woff = 0; for (u32 w = 0; w < wv; w++) woff += wtmp[w];
    u32 base = woff + inc - s8;
#pragma unroll
    for (int k = 0; k < 8; k++) { sbase[2047 - (t * 8 + k)] = base; base += a[k]; }
  }
  if (t == 0) {
    double nk = (double)NTOT - (double)sc->npruned;
    double mean = sc->sumW / nk;
    double var = (sc->sumW2 - 2.0 * mean * sc->sumW + nk * mean * mean) / (nk - 1.0);
    sc->stdf = (float)sqrt(var);
    u64 nfi = (u64)(0.1 * (double)sc->npruned);
    if (nfi < 1) nfi = 1;
    sc->nflip = nfi;
  }
}

// Route B: re-stream segments; LDS cursors pre-seeded from alloc+bdest.
__global__ __launch_bounds__(256) void k_route_b(const u32* __restrict__ segs,
                                                 const u32* __restrict__ segcnt,
                                                 const u32* __restrict__ alloc,
                                                 const u32* __restrict__ bdest,
                                                 u32* routed, u32 uk0, u32 uk1) {
  __shared__ u32 lcur[2048];
  u32 t = threadIdx.x;
  for (u32 j = t; j < 2048; j += 256) lcur[j] = alloc[j] + bdest[blockIdx.x * 2048 + j];
  __syncthreads();
#pragma unroll 1
  for (int sg = 0; sg < 16; sg++) {
    u32 wid = blockIdx.x * 16 + sg;
    u32 n = segcnt[wid]; if (n > WCAP) n = WCAP;
    const u32* sp = segs + (u64)wid * WCAP;
    for (u32 i = t; i < n; i += 256) {
      u32 idx = sp[i];
      u32 sup = (jax_bits32(uk0, uk1, idx) >> 18) - PBASE;
      u32 pos = atomicAdd(&lcur[sup], 1u);
      if (pos < ROUTED_CAP) routed[pos] = idx;
    }
  }
}

// 512-bin suffix-exclusive scan (256 threads, 2 bins each)
__device__ inline void suf512(const u32* cnt, u32* suf, u32* wtmp) {
  u32 t = threadIdx.x, lane = t & 63, wv = t >> 6;
  u32 a0 = cnt[511 - t * 2], a1 = cnt[510 - t * 2];
  u32 s = a0 + a1;
  u32 inc = s;
#pragma unroll
  for (int o = 1; o < 64; o <<= 1) { u32 v = (u32)__shfl_up((int)inc, o); if (lane >= (u32)o) inc += v; }
  if (lane == 63) wtmp[wv] = inc;
  __syncthreads();
  u32 woff = 0;
  for (u32 w = 0; w < wv; w++) woff += wtmp[w];
  u32 base = woff + inc - s;
  suf[511 - t * 2] = base;
  suf[510 - t * 2] = base + a0;
  __syncthreads();
}

// Rank: one block per 512-bin super. Winners write flip value: bf16 into wbf
// (WBF path) or fp32 into W (fallback).
template<int WBF>
__global__ __launch_bounds__(256) void k_rank(float* __restrict__ W,
                                              u16* __restrict__ wbf,
                                              const u32* __restrict__ colsum,
                                              const u32* __restrict__ alloc,
                                              const u32* __restrict__ sbase,
                                              const u32* __restrict__ routed,
                                              const Scalars* __restrict__ sc,
                                              u32 uk0, u32 uk1, u32 vk0, u32 vk1) {
  u32 p = blockIdx.x;
  u32 n = colsum[p]; if (n == 0) return;
  if (n > RCAP) n = RCAP;
  u64 nflip = sc->nflip;
  u32 rbase = sbase[p];
  if ((u64)rbase >= nflip) return;
  __shared__ u32 sIdx[RCAP];
  __shared__ u16 sFine[RCAP];
  __shared__ u32 pIdx[RCAP];
  __shared__ u32 hist[512], gbase[512], cur[512], wtmp[4];
  u32 t = threadIdx.x;
  for (u32 j = t; j < 512; j += 256) hist[j] = 0;
  __syncthreads();
  const u32* src = routed + alloc[p];
  for (u32 i = t; i < n; i += 256) {
    u32 idx = src[i];
    u32 f = (jax_bits32(uk0, uk1, idx) >> 9) & 511u;
    sIdx[i] = idx;
    sFine[i] = (u16)f;
    atomicAdd(&hist[f], 1u);
  }
  __syncthreads();
  suf512(hist, gbase, wtmp);         // gbase[f] = # members with fine > f
  for (u32 j = t; j < 512; j += 256) cur[j] = gbase[j];
  __syncthreads();
  for (u32 i = t; i < n; i += 256) {
    u32 pos = atomicAdd(&cur[sFine[i]], 1u);
    pIdx[pos] = sIdx[i];
  }
  __syncthreads();
  float stdf = sc->stdf;
  for (u32 i = t; i < n; i += 256) {
    u32 f = sFine[i];
    u32 g0 = gbase[f], g1 = g0 + hist[f];
    u32 v = sIdx[i];
    u32 ord = 0;
    for (u32 q = g0; q < g1; q++) ord += (pIdx[q] < v) ? 1u : 0u;
    u64 rank = (u64)rbase + g0 + ord;
    if (rank >= nflip) continue;
    u32 bits = jax_bits32(vk0, vk1, (u32)rank);
    union { u32 u; float fl; } cv; cv.u = 0x3F800000u | (bits >> 9);
    float fu = cv.fl - 1.0f;               // uniform [0,1)
    const float lo = -0.99999994f;         // nextafter(-1,0); (1-lo) rounds to 2.0f
    float u2 = fmaxf(lo, fu * 2.0f + lo);  // uniform [lo, 1)
    float nrm = 1.41421354f * erfinv32(u2);
    float val = (nrm * stdf) * 0.1f;
    if (WBF) wbf[v] = f2bf(val);
    else     W[v] = val;
  }
}

// x fp32 -> bf16 once
__global__ __launch_bounds__(256) void k_xconv(const float* __restrict__ x, u16* __restrict__ xbf) {
  u32 i = blockIdx.x * blockDim.x + threadIdx.x;
  float4 v = ((const float4*)x)[i];
  ushort4 o; o.x = f2bf(v.x); o.y = f2bf(v.y); o.z = f2bf(v.z); o.w = f2bf(v.w);
  ((ushort4*)xbf)[i] = o;
}

typedef __bf16 bf16x8 __attribute__((ext_vector_type(8)));
typedef float f32x4 __attribute__((ext_vector_type(4)));

// GEMM2 (m97-structure): out[m][n] = sum_k x[m][k]*W[n][k], both operands bf16
// in memory. 128x128 tile, BK=64, 4 waves (2x2), global_load_lds width-16
// staging with XOR-swizzle (pre-swizzled global source + swizzled ds_read;
// LDS linear — both-sides-or-neither, rule #21). KSPLIT=8 -> 1024 blocks.
// Per K-step/wave: 8 gload_lds, 16 ds_read_b128, 32 MFMA.
__global__ __launch_bounds__(256, 3) void k_gemm2(const u16* __restrict__ xbf,
                                                  const u16* __restrict__ wbf,
                                                  float* __restrict__ outp) {
  __shared__ u16 As[128 * 64];   // 16 KB, linear (row-major [128][64])
  __shared__ u16 Bs[128 * 64];   // 16 KB
  u32 tid = threadIdx.x;
  u32 lane = tid & 63, wv = tid >> 6;
  u32 l8 = lane & 7;             // chunk index within row (8x 16B chunks)
  u32 lr = lane >> 3;            // row within 8-row issue
  u32 nrow = blockIdx.x * 128;
  u32 mrow = blockIdx.y * 128;
  u32 kbase = blockIdx.z * (8192u / KSPLIT);
  u32 wm = wv >> 1, wn = wv & 1;
  u32 r = lane & 15, q = lane >> 4;
  f32x4 acc[4][4];
#pragma unroll
  for (int i = 0; i < 4; i++)
#pragma unroll
    for (int j = 0; j < 4; j++) acc[i][j] = (f32x4){0.f, 0.f, 0.f, 0.f};

  for (u32 kb = kbase; kb < kbase + (8192u / KSPLIT); kb += 64u) {
    // --- stage: 4 issues/wave/operand; issue g covers rows g*8..g*8+7.
    // LDS[row][chunk j] holds global[row][chunk j ^ (row&7)] (involution).
#pragma unroll
    for (int j = 0; j < 4; j++) {
      u32 g = wv * 4 + (u32)j;
      u32 row = g * 8 + lr;
      u32 sc = ((l8 ^ (row & 7u)) * 8u);   // pre-swizzled source col (bf16)
      const u16* ga = xbf + (u64)(mrow + row) * 8192 + kb + sc;
      __builtin_amdgcn_global_load_lds((const u32*)ga, (u32*)&As[g * 512u], 16, 0, 0);
      const u16* gb = wbf + (u64)(nrow + row) * 8192 + kb + sc;
      __builtin_amdgcn_global_load_lds((const u32*)gb, (u32*)&Bs[g * 512u], 16, 0, 0);
    }
    __syncthreads();
    // --- compute from LDS (swizzled ds_read_b128: chunk ^= row&7 -> 2-way max)
#pragma unroll
    for (int ks = 0; ks < 2; ks++) {
      bf16x8 a[4], b[4];
      u32 ch = (u32)(ks * 4) + q;          // logical chunk = K-slab col/8
#pragma unroll
      for (int mt = 0; mt < 4; mt++) {
        u32 row = wm * 64 + (u32)mt * 16 + r;
        a[mt] = *(bf16x8*)&As[row * 64 + ((ch ^ (r & 7u)) * 8u)];
      }
#pragma unroll
      for (int nt = 0; nt < 4; nt++) {
        u32 row = wn * 64 + (u32)nt * 16 + r;
        b[nt] = *(bf16x8*)&Bs[row * 64 + ((ch ^ (r & 7u)) * 8u)];
      }
#pragma unroll
      for (int mt = 0; mt < 4; mt++)
#pragma unroll
        for (int nt = 0; nt < 4; nt++)
          acc[mt][nt] = __builtin_amdgcn_mfma_f32_16x16x32_bf16(a[mt], b[nt], acc[mt][nt], 0, 0, 0);
    }
    __syncthreads();
  }
  float* op = outp + (u64)blockIdx.z * 2097152u;
  u32 quad = lane >> 4, col = lane & 15;
#pragma unroll
  for (int mt = 0; mt < 4; mt++)
#pragma unroll
    for (int nt = 0; nt < 4; nt++) {
      u32 n = nrow + wn * 64 + (u32)nt * 16 + col;
#pragma unroll
      for (int rg = 0; rg < 4; rg++) {
        u32 m = mrow + wm * 64 + (u32)mt * 16 + quad * 4 + (u32)rg;
        op[(u64)m * 8192 + n] = acc[mt][nt][rg];
      }
    }
}

// Reduce split-K partials -> out (fully writes out; no memset needed).
__global__ __launch_bounds__(256) void k_redout(const float* __restrict__ part,
                                                float* __restrict__ out) {
  u32 i = blockIdx.x * 256 + threadIdx.x;   // f32x4 group; 2M/4 = 524288 total
  float4 s = ((const float4*)part)[i];
#pragma unroll
  for (int k = 1; k < KSPLIT; k++) {
    float4 v = ((const float4*)(part + (u64)k * 2097152u))[i];
    s.x += v.x; s.y += v.y; s.z += v.z; s.w += v.w;
  }
  ((float4*)out)[i] = s;
}

// Fallback GEMM (round-0 structure, f32 W in-loop convert, atomics). Only runs
// if ws too small for wbf; perf irrelevant, correctness preserved.
__global__ __launch_bounds__(256, 2) void k_gemm_fb(const u16* __restrict__ xbf,
                                                    const float* __restrict__ W,
                                                    float* __restrict__ out) {
  __shared__ u16 xs[256 * 72];
  __shared__ u16 wsm[64 * 72];
  u32 tid = threadIdx.x;
  u32 lane = tid & 63, wv = tid >> 6;
  u32 nt0 = blockIdx.x * 64;
  u32 kbase = blockIdx.y * 2048u;
  f32x4 acc[4][4];
#pragma unroll
  for (int i = 0; i < 4; i++)
#pragma unroll
    for (int j = 0; j < 4; j++) acc[i][j] = (f32x4){0.f, 0.f, 0.f, 0.f};
  for (u32 kb = kbase; kb < kbase + 2048u; kb += 64u) {
#pragma unroll
    for (int r8 = 0; r8 < 8; r8++) {
      u32 row = r8 * 32 + (tid >> 3);
      u32 kseg = (tid & 7) * 8;
      uint4 v = *(const uint4*)(xbf + (u64)row * 8192 + kb + kseg);
      *(uint4*)&xs[row * 72 + kseg] = v;
    }
#pragma unroll
    for (int rr = 0; rr < 4; rr++) {
      u32 f4 = rr * 256 + tid;
      u32 row = f4 >> 4;
      u32 kc = (f4 & 15) * 4;
      float4 v = *(const float4*)(W + (u64)(nt0 + row) * 8192 + kb + kc);
      ushort4 o; o.x = f2bf(v.x); o.y = f2bf(v.y); o.z = f2bf(v.z); o.w = f2bf(v.w);
      *(ushort4*)&wsm[row * 72 + kc] = o;
    }
    __syncthreads();
#pragma unroll
    for (int ks = 0; ks < 2; ks++) {
      bf16x8 a[4], b[4];
      u32 koff = ks * 32 + (lane >> 4) * 8;
      u32 rsel = lane & 15;
#pragma unroll
      for (int mt = 0; mt < 4; mt++) a[mt] = *(bf16x8*)&xs[(wv * 64 + mt * 16 + rsel) * 72 + koff];
#pragma unroll
      for (int nt = 0; nt < 4; nt++) b[nt] = *(bf16x8*)&wsm[(nt * 16 + rsel) * 72 + koff];
#pragma unroll
      for (int mt = 0; mt < 4; mt++)
#pragma unroll
        for (int nt = 0; nt < 4; nt++)
          acc[mt][nt] = __builtin_amdgcn_mfma_f32_16x16x32_bf16(a[mt], b[nt], acc[mt][nt], 0, 0, 0);
    }
    __syncthreads();
  }
  u32 quad = lane >> 4, col = lane & 15;
#pragma unroll
  for (int mt = 0; mt < 4; mt++)
#pragma unroll
    for (int nt = 0; nt < 4; nt++) {
      u32 n = nt0 + nt * 16 + col;
#pragma unroll
      for (int rg = 0; rg < 4; rg++) {
        u32 m = wv * 64 + mt * 16 + quad * 4 + rg;
        atomicAdd(&out[(u64)m * 8192 + n], acc[mt][nt][rg]);
      }
    }
}

extern "C" void kernel_launch(void* const* d_in, const int* in_sizes, int n_in,
                              void* d_out, int out_size, void* d_ws, size_t ws_size,
                              hipStream_t stream) {
  const float* x; float* W;
  if (in_sizes[0] == 2097152) { x = (const float*)d_in[0]; W = (float*)d_in[1]; }
  else                        { x = (const float*)d_in[1]; W = (float*)d_in[0]; }
  float* out = (float*)d_out;
  char* ws = (char*)d_ws;

  u32* colsum = (u32*)(ws + OFF_COLSUM);
  u32* alloc  = (u32*)(ws + OFF_ALLOC);
  u32* sbase  = (u32*)(ws + OFF_SBASE);
  Scalars* sc = (Scalars*)(ws + OFF_SC);
  u32* segcnt = (u32*)(ws + OFF_SEGCNT);
  u32* bhist  = (u32*)(ws + OFF_BHIST);
  u32* bdest  = (u32*)(ws + OFF_BDEST);
  u16* xbf    = (u16*)(ws + OFF_XBF);
  u32* segs   = (u32*)(ws + OFF_SEGS);
  u32* routed = (u32*)(ws + OFF_ROUTED);
  u16* wbf    = (u16*)(ws + OFF_WBF);
  float* outp = (float*)(ws + OFF_OUTP);

  bool usewbf = (ws_size >= (size_t)WS_NEED_WBF);

  // PARTITIONABLE split of key(42): key[i] = threefry(k=(0,42), counter=(0,i))
  u32 a0, a1, b0, b1;
  tf2x32(0u, 42u, 0u, 0u, a0, a1);   // ks -> uniform scores
  tf2x32(0u, 42u, 0u, 1u, b0, b1);   // kv -> normal vals

  hipMemsetAsync(sc, 0, sizeof(Scalars), stream);

  k_xconv<<<2048, 256, 0, stream>>>(x, xbf);
  k_pass1<<<1024, 256, 0, stream>>>(W, sc, segcnt, segs, a0, a1);
  if (usewbf) k_wconv<<<4096, 256, 0, stream>>>(W, wbf);
  k_route_a<<<256, 256, 0, stream>>>(segs, segcnt, bhist, a0, a1);
  k_colscan<<<2048, 256, 0, stream>>>(bhist, bdest, colsum);
  k_scan<<<1, 256, 0, stream>>>(colsum, sc, alloc, sbase);
  k_route_b<<<256, 256, 0, stream>>>(segs, segcnt, alloc, bdest, routed, a0, a1);
  if (usewbf) {
    k_rank<1><<<NSUP, 256, 0, stream>>>(W, wbf, colsum, alloc, sbase, routed, sc, a0, a1, b0, b1);
    dim3 g(64, 2, KSPLIT);
    k_gemm2<<<g, 256, 0, stream>>>(xbf, wbf, outp);
    k_redout<<<2048, 256, 0, stream>>>(outp, out);
  } else {
    k_rank<0><<<NSUP, 256, 0, stream>>>(W, wbf, colsum, alloc, sbase, routed, sc, a0, a1, b0, b1);
    hipMemsetAsync(out, 0, (size_t)out_size * 4, stream);
    dim3 g(128, 4);
    k_gemm_fb<<<g, 256, 0, stream>>>(xbf, W, out);
  }
}

// Round 5
// 1009.123 us; speedup vs baseline: 1.1569x; 1.0161x over previous
//
#include <hip/hip_runtime.h>

typedef unsigned int u32;
typedef unsigned long long u64;
typedef unsigned short u16;

#define NTOT   67108864u    // 8192*8192 = 2^26
#define T0P    7399424u     // candidate threshold (PBASE<<9); true cutoff ~7.5497M
#define PBASE  14452u       // T0P >> 9
#define NSUP   1932u        // supers of 512 fine bins each, covering [T0P, 2^23)
#define NWSEG  4096u        // per-wave segments (1024 pass1 blocks x 4 waves)
#define WCAP   2176u        // per-wave cap: mean 1739, sigma 39.4 -> +11.1 sigma
#define RCAP   4352u        // per-super cap: mean 3686, sigma 60.5 -> +11 sigma
#define KSPLIT 8            // gemm2 split-K (1024 blocks)
#define RBLK   512u         // route_a/route_b blocks (2 blocks/CU)
#define SEGPB  8            // segs per route block (RBLK*SEGPB = NWSEG)

struct Scalars {
  double sumW;
  double sumW2;
  u64 npruned;
  u64 nflip;
  float stdf;
  float pad;
};

// ---- ws layout (bytes) ----
#define OFF_COLSUM 0ull          // 2048 u32
#define OFF_ALLOC  8192ull       // 2048 u32
#define OFF_SBASE  16384ull      // 2048 u32
#define OFF_SC     24576ull      // 128 B
#define OFF_SEGCNT 24704ull      // 4096 u32 -> ends 41,088
#define OFF_BHIST  41216ull      // 512*2048*4 = 4,194,304 -> ends 4,235,520
#define OFF_BDEST  4235520ull    // 4,194,304 -> ends 8,429,824
#define OFF_XBF    8429824ull    // 256*8192*2 = 4,194,304 -> ends 12,624,128
#define OFF_SEGS   12624128ull   // 4096*2176*4 = 35,651,584 -> ends 48,275,712
#define OFF_ROUTED 48275712ull   // 8M u32 = 33,554,432 -> ends 81,830,144
#define OFF_WBF    81846400ull   // bf16 W copy: 134,217,728 -> ends 216,064,128
#define WS_NEED_WBF 216064128ull
#define ROUTED_CAP 8388608u      // expected 7.12M +- 2.5K -> +500 sigma
// gemm2 partials REUSE segs+routed (dead after k_rank):
// 12,624,128 + 8*8,388,608 = 79,732,992 < OFF_WBF  ok
#define OFF_OUTP   OFF_SEGS

// JAX Threefry-2x32, 20 rounds — verified vs known-answer vector
__host__ __device__ inline void tf2x32(u32 k0, u32 k1, u32 x0, u32 x1, u32& y0, u32& y1) {
  u32 ks2 = k0 ^ k1 ^ 0x1BD11BDAu;
  x0 += k0; x1 += k1;
#define TFR(r) { x0 += x1; x1 = (x1 << (r)) | (x1 >> (32 - (r))); x1 ^= x0; }
  TFR(13) TFR(15) TFR(26) TFR(6)  x0 += k1;  x1 += ks2 + 1u;
  TFR(17) TFR(29) TFR(16) TFR(24) x0 += ks2; x1 += k0 + 2u;
  TFR(13) TFR(15) TFR(26) TFR(6)  x0 += k0;  x1 += k1 + 3u;
  TFR(17) TFR(29) TFR(16) TFR(24) x0 += k1;  x1 += ks2 + 4u;
  TFR(13) TFR(15) TFR(26) TFR(6)  x0 += ks2; x1 += k0 + 5u;
#undef TFR
  y0 = x0; y1 = x1;
}

// Partitionable-mode bits for element i: counter (0, i), bits = y0 ^ y1
__device__ inline u32 jax_bits32(u32 k0, u32 k1, u32 i) {
  u32 y0, y1; tf2x32(k0, k1, 0u, i, y0, y1);
  return y0 ^ y1;
}

__device__ inline u16 f2bf(float f) {
  union { float f; u32 u; } c; c.f = f;
  u32 r = ((c.u >> 16) & 1u) + 0x7FFFu;   // RNE
  return (u16)((c.u + r) >> 16);
}

// XLA ErfInv (f32, Giles)
__device__ inline float erfinv32(float x) {
  float w = -log1pf(-x * x);
  float p;
  if (w < 5.0f) {
    w -= 2.5f;
    p = 2.81022636e-08f;
    p = fmaf(p, w, 3.43273939e-07f);
    p = fmaf(p, w, -3.5233877e-06f);
    p = fmaf(p, w, -4.39150654e-06f);
    p = fmaf(p, w, 0.00021858087f);
    p = fmaf(p, w, -0.00125372503f);
    p = fmaf(p, w, -0.00417768164f);
    p = fmaf(p, w, 0.246640727f);
    p = fmaf(p, w, 1.50140941f);
  } else {
    w = sqrtf(w) - 3.0f;
    p = -0.000200214257f;
    p = fmaf(p, w, 0.000100950558f);
    p = fmaf(p, w, 0.00134934322f);
    p = fmaf(p, w, -0.00367342844f);
    p = fmaf(p, w, 0.00573950773f);
    p = fmaf(p, w, -0.0076224613f);
    p = fmaf(p, w, 0.00943887047f);
    p = fmaf(p, w, 1.00167406f);
    p = fmaf(p, w, 2.83297682f);
  }
  return p * x;
}

// Fused pass1 + wconv via heterogeneous grid: blocks 0..1023 run the verbatim
// round-0 pass1 loop (VALU-bound); blocks 1024..2047 run the wconv stream
// (memory-bound). Complementary pipes co-scheduled per CU -> time ~ max not sum.
__global__ __launch_bounds__(256) void k_pass1w(const float* __restrict__ W,
                                                u16* __restrict__ wbf, Scalars* sc,
                                                u32* segcnt, u32* segs,
                                                u32 uk0, u32 uk1) {
  u32 t = threadIdx.x;
  u32 bid = blockIdx.x;
  if (bid < 1024u) {
    // ---- pass1 half (round-0 verbatim; best measured 258us standalone) ----
    u32 gid = bid * 256 + t;
    u32 lane = t & 63;
    u32 wid = gid >> 6;
    u32* wseg = segs + (u64)wid * WCAP;
    u32 wbase = 0;                     // wave-uniform cursor, kept in registers
    double s = 0.0, s2 = 0.0; u32 cnt = 0;
    const u32 stride4 = 1024u * 256u * 4u;
    for (u32 b4 = gid * 4; b4 < NTOT; b4 += stride4) {
      float4 w4 = *(const float4*)(W + b4);
      u32 sb0 = jax_bits32(uk0, uk1, b4 + 0) >> 9;   // 4 independent chains
      u32 sb1 = jax_bits32(uk0, uk1, b4 + 1) >> 9;
      u32 sb2 = jax_bits32(uk0, uk1, b4 + 2) >> 9;
      u32 sb3 = jax_bits32(uk0, uk1, b4 + 3) >> 9;
      float we[4] = {w4.x, w4.y, w4.z, w4.w};
      u32 sbv[4] = {sb0, sb1, sb2, sb3};
      u32 cand[4]; u32 nc = 0;
#pragma unroll
      for (int e = 0; e < 4; e++) {
        float w = we[e];
        s  += (double)w;
        s2 += (double)w * (double)w;
        bool pr = (w == 0.0f);
        cnt += pr ? 1u : 0u;
        if (pr && sbv[e] >= T0P) { cand[nc] = b4 + e; nc++; }
      }
      u32 inc = nc;                    // wave inclusive scan of per-lane counts
#pragma unroll
      for (int o = 1; o < 64; o <<= 1) { u32 v = (u32)__shfl_up((int)inc, o); if (lane >= (u32)o) inc += v; }
      u32 tot = (u32)__shfl((int)inc, 63);
      u32 pos = wbase + inc - nc;
      for (u32 k2 = 0; k2 < nc; k2++)
        if (pos + k2 < WCAP) wseg[pos + k2] = cand[k2];
      wbase += tot;
    }
    for (int o = 32; o > 0; o >>= 1) {
      s += __shfl_down(s, o); s2 += __shfl_down(s2, o); cnt += __shfl_down(cnt, o);
    }
    if (lane == 0) {
      atomicAdd(&sc->sumW, s);
      atomicAdd(&sc->sumW2, s2);
      atomicAdd(&sc->npruned, (u64)cnt);
      segcnt[wid] = (wbase > WCAP) ? WCAP : wbase;
    }
  } else {
    // ---- wconv half: W f32 -> bf16 stream (memory-bound) ----
    u32 i0 = (bid - 1024u) * 256 + t;
    const u32 stride = 1024u * 256u;
    for (u32 g = i0; g < NTOT / 8; g += stride) {
      const float4* p = (const float4*)(W + (u64)g * 8);
      float4 a = p[0], b = p[1];
      uint4 o;
      o.x = (u32)f2bf(a.x) | ((u32)f2bf(a.y) << 16);
      o.y = (u32)f2bf(a.z) | ((u32)f2bf(a.w) << 16);
      o.z = (u32)f2bf(b.x) | ((u32)f2bf(b.y) << 16);
      o.w = (u32)f2bf(b.z) | ((u32)f2bf(b.w) << 16);
      *(uint4*)(wbf + (u64)g * 8) = o;
    }
  }
}

// Route A: 512 blocks x 8 segs (2 blocks/CU -> latency hidden vs 256-block
// version's 1 wave/SIMD). Per-block super-histogram -> bhist[block][2048].
__global__ __launch_bounds__(256) void k_route_a(const u32* __restrict__ segs,
                                                 const u32* __restrict__ segcnt,
                                                 u32* bhist, u32 uk0, u32 uk1) {
  __shared__ u32 lhist[2048];
  u32 t = threadIdx.x;
  for (u32 j = t; j < 2048; j += 256) lhist[j] = 0;
  __syncthreads();
#pragma unroll 1
  for (int sg = 0; sg < SEGPB; sg++) {
    u32 wid = blockIdx.x * SEGPB + sg;
    u32 n = segcnt[wid]; if (n > WCAP) n = WCAP;
    const u32* sp = segs + (u64)wid * WCAP;
    for (u32 i = t; i < n; i += 256) {
      u32 sup = (jax_bits32(uk0, uk1, sp[i]) >> 18) - PBASE;
      atomicAdd(&lhist[sup], 1u);
    }
  }
  __syncthreads();
  for (u32 j = t; j < 2048; j += 256) bhist[blockIdx.x * 2048 + j] = lhist[j];
}

// Column scan: per super s, exclusive prefix of bhist[b][s] over 512 blocks
// (2 rows/thread) + column totals.
__global__ __launch_bounds__(256) void k_colscan(const u32* __restrict__ bhist,
                                                 u32* bdest, u32* colsum) {
  __shared__ u32 wtmp[4];
  u32 s = blockIdx.x, t = threadIdx.x, lane = t & 63, wv = t >> 6;
  u32 v0 = bhist[(t * 2 + 0) * 2048 + s];
  u32 v1 = bhist[(t * 2 + 1) * 2048 + s];
  u32 pr = v0 + v1;
  u32 inc = pr;
#pragma unroll
  for (int o = 1; o < 64; o <<= 1) { u32 x = (u32)__shfl_up((int)inc, o); if (lane >= (u32)o) inc += x; }
  if (lane == 63) wtmp[wv] = inc;
  __syncthreads();
  u32 woff = 0;
  for (u32 w = 0; w < wv; w++) woff += wtmp[w];
  u32 base = woff + inc - pr;
  bdest[(t * 2 + 0) * 2048 + s] = base;
  bdest[(t * 2 + 1) * 2048 + s] = base + v0;
  if (t == 255) colsum[s] = woff + inc;
}

// Scalars + 2048-wide prefix (alloc = routed layout) & suffix (sbase = rank base).
__global__ __launch_bounds__(256) void k_scan(const u32* __restrict__ colsum, Scalars* sc,
                                              u32* alloc, u32* sbase) {
  __shared__ u32 h[2048];
  __shared__ u32 wtmp[4];
  u32 t = threadIdx.x, lane = t & 63, wv = t >> 6;
  for (u32 j = t; j < 2048; j += 256) h[j] = colsum[j];
  __syncthreads();
  {
    u32 a[8]; u32 s8 = 0;
#pragma unroll
    for (int k = 0; k < 8; k++) { a[k] = h[t * 8 + k]; s8 += a[k]; }
    u32 inc = s8;
#pragma unroll
    for (int o = 1; o < 64; o <<= 1) { u32 v = (u32)__shfl_up((int)inc, o); if (lane >= (u32)o) inc += v; }
    if (lane == 63) wtmp[wv] = inc;
    __syncthreads();
    u32 woff = 0; for (u32 w = 0; w < wv; w++) woff += wtmp[w];
    u32 base = woff + inc - s8;
#pragma unroll
    for (int k = 0; k < 8; k++) { alloc[t * 8 + k] = base; base += a[k]; }
    __syncthreads();
  }
  {
    u32 a[8]; u32 s8 = 0;
#pragma unroll
    for (int k = 0; k < 8; k++) { a[k] = h[2047 - (t * 8 + k)]; s8 += a[k]; }
    u32 inc = s8;
#pragma unroll
    for (int o = 1; o < 64; o <<= 1) { u32 v = (u32)__shfl_up((int)inc, o); if (lane >= (u32)o) inc += v; }
    if (lane == 63) wtmp[wv] = inc;
    __syncthreads();
    u32 woff = 0; for (u32 w = 0; w < wv; w++) woff += wtmp[w];
    u32 base = woff + inc - s8;
#pragma unroll
    for (int k = 0; k < 8; k++) { sbase[2047 - (t * 8 + k)] = base; base += a[k]; }
  }
  if (t == 0) {
    double nk = (double)NTOT - (double)sc->npruned;
    double mean = sc->sumW / nk;
    double var = (sc->sumW2 - 2.0 * mean * sc->sumW + nk * mean * mean) / (nk - 1.0);
    sc->stdf = (float)sqrt(var);
    u64 nfi = (u64)(0.1 * (double)sc->npruned);
    if (nfi < 1) nfi = 1;
    sc->nflip = nfi;
  }
}

// Route B: re-stream segments; LDS cursors pre-seeded from alloc+bdest.
__global__ __launch_bounds__(256) void k_route_b(const u32* __restrict__ segs,
                                                 const u32* __restrict__ segcnt,
                                                 const u32* __restrict__ alloc,
                                                 const u32* __restrict__ bdest,
                                                 u32* routed, u32 uk0, u32 uk1) {
  __shared__ u32 lcur[2048];
  u32 t = threadIdx.x;
  for (u32 j = t; j < 2048; j += 256) lcur[j] = alloc[j] + bdest[blockIdx.x * 2048 + j];
  __syncthreads();
#pragma unroll 1
  for (int sg = 0; sg < SEGPB; sg++) {
    u32 wid = blockIdx.x * SEGPB + sg;
    u32 n = segcnt[wid]; if (n > WCAP) n = WCAP;
    const u32* sp = segs + (u64)wid * WCAP;
    for (u32 i = t; i < n; i += 256) {
      u32 idx = sp[i];
      u32 sup = (jax_bits32(uk0, uk1, idx) >> 18) - PBASE;
      u32 pos = atomicAdd(&lcur[sup], 1u);
      if (pos < ROUTED_CAP) routed[pos] = idx;
    }
  }
}

// 512-bin suffix-exclusive scan (256 threads, 2 bins each)
__device__ inline void suf512(const u32* cnt, u32* suf, u32* wtmp) {
  u32 t = threadIdx.x, lane = t & 63, wv = t >> 6;
  u32 a0 = cnt[511 - t * 2], a1 = cnt[510 - t * 2];
  u32 s = a0 + a1;
  u32 inc = s;
#pragma unroll
  for (int o = 1; o < 64; o <<= 1) { u32 v = (u32)__shfl_up((int)inc, o); if (lane >= (u32)o) inc += v; }
  if (lane == 63) wtmp[wv] = inc;
  __syncthreads();
  u32 woff = 0;
  for (u32 w = 0; w < wv; w++) woff += wtmp[w];
  u32 base = woff + inc - s;
  suf[511 - t * 2] = base;
  suf[510 - t * 2] = base + a0;
  __syncthreads();
}

// Rank: one block per 512-bin super. Winners write flip value: bf16 into wbf
// (WBF path) or fp32 into W (fallback).
template<int WBF>
__global__ __launch_bounds__(256) void k_rank(float* __restrict__ W,
                                              u16* __restrict__ wbf,
                                              const u32* __restrict__ colsum,
                                              const u32* __restrict__ alloc,
                                              const u32* __restrict__ sbase,
                                              const u32* __restrict__ routed,
                                              const Scalars* __restrict__ sc,
                                              u32 uk0, u32 uk1, u32 vk0, u32 vk1) {
  u32 p = blockIdx.x;
  u32 n = colsum[p]; if (n == 0) return;
  if (n > RCAP) n = RCAP;
  u64 nflip = sc->nflip;
  u32 rbase = sbase[p];
  if ((u64)rbase >= nflip) return;
  __shared__ u32 sIdx[RCAP];
  __shared__ u16 sFine[RCAP];
  __shared__ u32 pIdx[RCAP];
  __shared__ u32 hist[512], gbase[512], cur[512], wtmp[4];
  u32 t = threadIdx.x;
  for (u32 j = t; j < 512; j += 256) hist[j] = 0;
  __syncthreads();
  const u32* src = routed + alloc[p];
  for (u32 i = t; i < n; i += 256) {
    u32 idx = src[i];
    u32 f = (jax_bits32(uk0, uk1, idx) >> 9) & 511u;
    sIdx[i] = idx;
    sFine[i] = (u16)f;
    atomicAdd(&hist[f], 1u);
  }
  __syncthreads();
  suf512(hist, gbase, wtmp);         // gbase[f] = # members with fine > f
  for (u32 j = t; j < 512; j += 256) cur[j] = gbase[j];
  __syncthreads();
  for (u32 i = t; i < n; i += 256) {
    u32 pos = atomicAdd(&cur[sFine[i]], 1u);
    pIdx[pos] = sIdx[i];
  }
  __syncthreads();
  float stdf = sc->stdf;
  for (u32 i = t; i < n; i += 256) {
    u32 f = sFine[i];
    u32 g0 = gbase[f], g1 = g0 + hist[f];
    u32 v = sIdx[i];
    u32 ord = 0;
    for (u32 q = g0; q < g1; q++) ord += (pIdx[q] < v) ? 1u : 0u;
    u64 rank = (u64)rbase + g0 + ord;
    if (rank >= nflip) continue;
    u32 bits = jax_bits32(vk0, vk1, (u32)rank);
    union { u32 u; float fl; } cv; cv.u = 0x3F800000u | (bits >> 9);
    float fu = cv.fl - 1.0f;               // uniform [0,1)
    const float lo = -0.99999994f;         // nextafter(-1,0); (1-lo) rounds to 2.0f
    float u2 = fmaxf(lo, fu * 2.0f + lo);  // uniform [lo, 1)
    float nrm = 1.41421354f * erfinv32(u2);
    float val = (nrm * stdf) * 0.1f;
    if (WBF) wbf[v] = f2bf(val);
    else     W[v] = val;
  }
}

// x fp32 -> bf16 once
__global__ __launch_bounds__(256) void k_xconv(const float* __restrict__ x, u16* __restrict__ xbf) {
  u32 i = blockIdx.x * blockDim.x + threadIdx.x;
  float4 v = ((const float4*)x)[i];
  ushort4 o; o.x = f2bf(v.x); o.y = f2bf(v.y); o.z = f2bf(v.z); o.w = f2bf(v.w);
  ((ushort4*)xbf)[i] = o;
}

typedef __bf16 bf16x8 __attribute__((ext_vector_type(8)));
typedef float f32x4 __attribute__((ext_vector_type(4)));

// GEMM2 (m97-structure): out[m][n] = sum_k x[m][k]*W[n][k], both operands bf16
// in memory. 128x128 tile, BK=64, 4 waves (2x2), global_load_lds width-16
// staging with XOR-swizzle (pre-swizzled global source + swizzled ds_read;
// LDS linear — both-sides-or-neither, rule #21). KSPLIT=8 -> 1024 blocks.
__global__ __launch_bounds__(256, 3) void k_gemm2(const u16* __restrict__ xbf,
                                                  const u16* __restrict__ wbf,
                                                  float* __restrict__ outp) {
  __shared__ u16 As[128 * 64];   // 16 KB, linear (row-major [128][64])
  __shared__ u16 Bs[128 * 64];   // 16 KB
  u32 tid = threadIdx.x;
  u32 lane = tid & 63, wv = tid >> 6;
  u32 l8 = lane & 7;             // chunk index within row (8x 16B chunks)
  u32 lr = lane >> 3;            // row within 8-row issue
  u32 nrow = blockIdx.x * 128;
  u32 mrow = blockIdx.y * 128;
  u32 kbase = blockIdx.z * (8192u / KSPLIT);
  u32 wm = wv >> 1, wn = wv & 1;
  u32 r = lane & 15, q = lane >> 4;
  f32x4 acc[4][4];
#pragma unroll
  for (int i = 0; i < 4; i++)
#pragma unroll
    for (int j = 0; j < 4; j++) acc[i][j] = (f32x4){0.f, 0.f, 0.f, 0.f};

  for (u32 kb = kbase; kb < kbase + (8192u / KSPLIT); kb += 64u) {
#pragma unroll
    for (int j = 0; j < 4; j++) {
      u32 g = wv * 4 + (u32)j;
      u32 row = g * 8 + lr;
      u32 sc = ((l8 ^ (row & 7u)) * 8u);   // pre-swizzled source col (bf16)
      const u16* ga = xbf + (u64)(mrow + row) * 8192 + kb + sc;
      __builtin_amdgcn_global_load_lds((const u32*)ga, (u32*)&As[g * 512u], 16, 0, 0);
      const u16* gb = wbf + (u64)(nrow + row) * 8192 + kb + sc;
      __builtin_amdgcn_global_load_lds((const u32*)gb, (u32*)&Bs[g * 512u], 16, 0, 0);
    }
    __syncthreads();
#pragma unroll
    for (int ks = 0; ks < 2; ks++) {
      bf16x8 a[4], b[4];
      u32 ch = (u32)(ks * 4) + q;          // logical chunk = K-slab col/8
#pragma unroll
      for (int mt = 0; mt < 4; mt++) {
        u32 row = wm * 64 + (u32)mt * 16 + r;
        a[mt] = *(bf16x8*)&As[row * 64 + ((ch ^ (r & 7u)) * 8u)];
      }
#pragma unroll
      for (int nt = 0; nt < 4; nt++) {
        u32 row = wn * 64 + (u32)nt * 16 + r;
        b[nt] = *(bf16x8*)&Bs[row * 64 + ((ch ^ (r & 7u)) * 8u)];
      }
#pragma unroll
      for (int mt = 0; mt < 4; mt++)
#pragma unroll
        for (int nt = 0; nt < 4; nt++)
          acc[mt][nt] = __builtin_amdgcn_mfma_f32_16x16x32_bf16(a[mt], b[nt], acc[mt][nt], 0, 0, 0);
    }
    __syncthreads();
  }
  float* op = outp + (u64)blockIdx.z * 2097152u;
  u32 quad = lane >> 4, col = lane & 15;
#pragma unroll
  for (int mt = 0; mt < 4; mt++)
#pragma unroll
    for (int nt = 0; nt < 4; nt++) {
      u32 n = nrow + wn * 64 + (u32)nt * 16 + col;
#pragma unroll
      for (int rg = 0; rg < 4; rg++) {
        u32 m = mrow + wm * 64 + (u32)mt * 16 + quad * 4 + (u32)rg;
        op[(u64)m * 8192 + n] = acc[mt][nt][rg];
      }
    }
}

// Reduce split-K partials -> out (fully writes out; no memset needed).
__global__ __launch_bounds__(256) void k_redout(const float* __restrict__ part,
                                                float* __restrict__ out) {
  u32 i = blockIdx.x * 256 + threadIdx.x;   // f32x4 group; 2M/4 = 524288 total
  float4 s = ((const float4*)part)[i];
#pragma unroll
  for (int k = 1; k < KSPLIT; k++) {
    float4 v = ((const float4*)(part + (u64)k * 2097152u))[i];
    s.x += v.x; s.y += v.y; s.z += v.z; s.w += v.w;
  }
  ((float4*)out)[i] = s;
}

// Fallback GEMM (reg-staged f32 W, atomics). Only if ws too small for wbf.
__global__ __launch_bounds__(256, 2) void k_gemm_fb(const u16* __restrict__ xbf,
                                                    const float* __restrict__ W,
                                                    float* __restrict__ out) {
  __shared__ u16 xs[256 * 72];
  __shared__ u16 wsm[64 * 72];
  u32 tid = threadIdx.x;
  u32 lane = tid & 63, wv = tid >> 6;
  u32 nt0 = blockIdx.x * 64;
  u32 kbase = blockIdx.y * 2048u;
  f32x4 acc[4][4];
#pragma unroll
  for (int i = 0; i < 4; i++)
#pragma unroll
    for (int j = 0; j < 4; j++) acc[i][j] = (f32x4){0.f, 0.f, 0.f, 0.f};
  for (u32 kb = kbase; kb < kbase + 2048u; kb += 64u) {
#pragma unroll
    for (int r8 = 0; r8 < 8; r8++) {
      u32 row = r8 * 32 + (tid >> 3);
      u32 kseg = (tid & 7) * 8;
      uint4 v = *(const uint4*)(xbf + (u64)row * 8192 + kb + kseg);
      *(uint4*)&xs[row * 72 + kseg] = v;
    }
#pragma unroll
    for (int rr = 0; rr < 4; rr++) {
      u32 f4 = rr * 256 + tid;
      u32 row = f4 >> 4;
      u32 kc = (f4 & 15) * 4;
      float4 v = *(const float4*)(W + (u64)(nt0 + row) * 8192 + kb + kc);
      ushort4 o; o.x = f2bf(v.x); o.y = f2bf(v.y); o.z = f2bf(v.z); o.w = f2bf(v.w);
      *(ushort4*)&wsm[row * 72 + kc] = o;
    }
    __syncthreads();
#pragma unroll
    for (int ks = 0; ks < 2; ks++) {
      bf16x8 a[4], b[4];
      u32 koff = ks * 32 + (lane >> 4) * 8;
      u32 rsel = lane & 15;
#pragma unroll
      for (int mt = 0; mt < 4; mt++) a[mt] = *(bf16x8*)&xs[(wv * 64 + mt * 16 + rsel) * 72 + koff];
#pragma unroll
      for (int nt = 0; nt < 4; nt++) b[nt] = *(bf16x8*)&wsm[(nt * 16 + rsel) * 72 + koff];
#pragma unroll
      for (int mt = 0; mt < 4; mt++)
#pragma unroll
        for (int nt = 0; nt < 4; nt++)
          acc[mt][nt] = __builtin_amdgcn_mfma_f32_16x16x32_bf16(a[mt], b[nt], acc[mt][nt], 0, 0, 0);
    }
    __syncthreads();
  }
  u32 quad = lane >> 4, col = lane & 15;
#pragma unroll
  for (int mt = 0; mt < 4; mt++)
#pragma unroll
    for (int nt = 0; nt < 4; nt++) {
      u32 n = nt0 + nt * 16 + col;
#pragma unroll
      for (int rg = 0; rg < 4; rg++) {
        u32 m = wv * 64 + mt * 16 + quad * 4 + rg;
        atomicAdd(&out[(u64)m * 8192 + n], acc[mt][nt][rg]);
      }
    }
}

extern "C" void kernel_launch(void* const* d_in, const int* in_sizes, int n_in,
                              void* d_out, int out_size, void* d_ws, size_t ws_size,
                              hipStream_t stream) {
  const float* x; float* W;
  if (in_sizes[0] == 2097152) { x = (const float*)d_in[0]; W = (float*)d_in[1]; }
  else                        { x = (const float*)d_in[1]; W = (float*)d_in[0]; }
  float* out = (float*)d_out;
  char* ws = (char*)d_ws;

  u32* colsum = (u32*)(ws + OFF_COLSUM);
  u32* alloc  = (u32*)(ws + OFF_ALLOC);
  u32* sbase  = (u32*)(ws + OFF_SBASE);
  Scalars* sc = (Scalars*)(ws + OFF_SC);
  u32* segcnt = (u32*)(ws + OFF_SEGCNT);
  u32* bhist  = (u32*)(ws + OFF_BHIST);
  u32* bdest  = (u32*)(ws + OFF_BDEST);
  u16* xbf    = (u16*)(ws + OFF_XBF);
  u32* segs   = (u32*)(ws + OFF_SEGS);
  u32* routed = (u32*)(ws + OFF_ROUTED);
  u16* wbf    = (u16*)(ws + OFF_WBF);
  float* outp = (float*)(ws + OFF_OUTP);

  bool usewbf = (ws_size >= (size_t)WS_NEED_WBF);

  // PARTITIONABLE split of key(42): key[i] = threefry(k=(0,42), counter=(0,i))
  u32 a0, a1, b0, b1;
  tf2x32(0u, 42u, 0u, 0u, a0, a1);   // ks -> uniform scores
  tf2x32(0u, 42u, 0u, 1u, b0, b1);   // kv -> normal vals

  hipMemsetAsync(sc, 0, sizeof(Scalars), stream);

  k_xconv<<<2048, 256, 0, stream>>>(x, xbf);
  // heterogeneous grid: 1024 pass1 blocks (+1024 wconv blocks iff WBF path)
  k_pass1w<<<usewbf ? 2048 : 1024, 256, 0, stream>>>(W, wbf, sc, segcnt, segs, a0, a1);
  k_route_a<<<RBLK, 256, 0, stream>>>(segs, segcnt, bhist, a0, a1);
  k_colscan<<<2048, 256, 0, stream>>>(bhist, bdest, colsum);
  k_scan<<<1, 256, 0, stream>>>(colsum, sc, alloc, sbase);
  k_route_b<<<RBLK, 256, 0, stream>>>(segs, segcnt, alloc, bdest, routed, a0, a1);
  if (usewbf) {
    k_rank<1><<<NSUP, 256, 0, stream>>>(W, wbf, colsum, alloc, sbase, routed, sc, a0, a1, b0, b1);
    dim3 g(64, 2, KSPLIT);
    k_gemm2<<<g, 256, 0, stream>>>(xbf, wbf, outp);
    k_redout<<<2048, 256, 0, stream>>>(outp, out);
  } else {
    k_rank<0><<<NSUP, 256, 0, stream>>>(W, wbf, colsum, alloc, sbase, routed, sc, a0, a1, b0, b1);
    hipMemsetAsync(out, 0, (size_t)out_size * 4, stream);
    dim3 g(128, 4);
    k_gemm_fb<<<g, 256, 0, stream>>>(xbf, W, out);
  }
}